// Round 3
// baseline (10225.231 us; speedup 1.0000x reference)
//
#include <hip/hip_runtime.h>
#include <cmath>

#ifndef M_PI
#define M_PI 3.14159265358979323846
#endif

#define T_LEN   160000
#define STRIDE_ 1024
#define NSEG    155      // (160000 - 2048) / 1024 + 1
#define NBLK    156      // blocks of 1024 covering [0, 159744); tail 256 samples unused by unfold
#define ROWS    32
#define NBANDS  8

struct AllCoefs {
    float h[NBANDS][5];   // b0 b1 b2 a1 a2 (a0-normalized, f32-cast like np.float32)
    float l[NBANDS][5];
};

// fp32 DF-I biquad with LLVM/clang FMA-contraction pattern applied to the
// left-associated reference expression
//   y = b0*x + b1*x1 + b2*x2 - a1*y1 - a2*y2
// contract: s1 = fma(b0,x, b1*x1); s2 = fma(b2,x2,s1);
//           s3 = fma(-a1,y1,s2);   y  = fma(-a2,y2,s3)
// Exact-coefficient filters (band0 HP, band7 LP: 1,±2,1,±2,1) are invariant
// to contraction, so this only changes rounding in the stable stages — which
// is precisely what seeds band 7's Nyquist-noise realization.
__device__ __forceinline__ float bq32(float x,
                                      const float b0, const float b1, const float b2,
                                      const float na1, const float na2,
                                      float& x1, float& x2, float& y1, float& y2) {
    float s1 = __fmaf_rn(b0, x, __fmul_rn(b1, x1));
    float s2 = __fmaf_rn(b2, x2, s1);
    float s3 = __fmaf_rn(na1, y1, s2);
    float y  = __fmaf_rn(na2, y2, s3);
    x2 = x1; x1 = x;
    y2 = y1; y1 = y;
    return y;
}

// Weighting biquad b=(1,-2,1), a=(1,-1.8f,0.81f). b-products are exact
// (powers of two), so fused and strict forms agree there; a-terms contracted.
__device__ __forceinline__ void wstep(float x, float& x1, float& x2,
                                      float& y1, float& y2, float& acc) {
    const float NA1 =  1.79999995231628417969f; // -np.float32(-1.8)
    const float NA2 = -0.810000002384185791f;   // -np.float32(0.81)
    float s1 = __fadd_rn(x, __fmul_rn(-2.0f, x1));  // exact product
    float s2 = __fadd_rn(s1, x2);                   // exact product (b2=1)
    float s3 = __fmaf_rn(NA1, y1, s2);
    float y  = __fmaf_rn(NA2, y2, s3);
    x2 = x1; x1 = x;
    y2 = y1; y1 = y;
    acc = __fmaf_rn(y, y, acc);
}

// One thread = one (band, src, row) chain. block b == band b (64 threads: src=tid>>5, row=tid&31).
__global__ __launch_bounds__(64, 1)
void tf_filter_kernel(const float* __restrict__ sig, const float* __restrict__ wm,
                      float* __restrict__ loud, AllCoefs C) {
    const int band = blockIdx.x;
    const int tid  = threadIdx.x;
    const int src  = tid >> 5;     // 0 = signal, 1 = watermark
    const int row  = tid & 31;

    const float* __restrict__ x = (src == 0 ? sig : wm) + (size_t)row * T_LEN;
    float* __restrict__ out = loud + ((size_t)(band * 2 + src) * ROWS + row) * NSEG;

    const float hb0 = C.h[band][0], hb1 = C.h[band][1], hb2 = C.h[band][2];
    const float hna1 = -C.h[band][3], hna2 = -C.h[band][4];
    const float lb0 = C.l[band][0], lb1 = C.l[band][1], lb2 = C.l[band][2];
    const float lna1 = -C.l[band][3], lna2 = -C.l[band][4];

    float hx1=0.f,hx2=0.f,hy1=0.f,hy2=0.f;          // highpass state
    float lx1=0.f,lx2=0.f,ly1=0.f,ly2=0.f;          // lowpass state
    float ax1=0.f,ax2=0.f,ay1=0.f,ay2=0.f,aacc=0.f; // weighting, even-parity segments
    float bx1=0.f,bx2=0.f,by1=0.f,by2=0.f,bacc=0.f; // weighting, odd-parity segments

    for (int b = 0; b < NBLK; ++b) {
        // Segment j=b starts at this block (spans blocks b and b+1); reset its state.
        if (b < NSEG) {
            if ((b & 1) == 0) { ax1=0.f; ax2=0.f; ay1=0.f; ay2=0.f; aacc=0.f; }
            else              { bx1=0.f; bx2=0.f; by1=0.f; by2=0.f; bacc=0.f; }
        }
        const float4* __restrict__ xp = (const float4*)(x + (size_t)b * STRIDE_);
        for (int i = 0; i < STRIDE_ / 4; ++i) {
            float4 v = xp[i];
            float y;
            y = bq32(v.x, hb0,hb1,hb2,hna1,hna2, hx1,hx2,hy1,hy2);
            y = bq32(y,   lb0,lb1,lb2,lna1,lna2, lx1,lx2,ly1,ly2);
            wstep(y, ax1,ax2,ay1,ay2,aacc);
            wstep(y, bx1,bx2,by1,by2,bacc);

            y = bq32(v.y, hb0,hb1,hb2,hna1,hna2, hx1,hx2,hy1,hy2);
            y = bq32(y,   lb0,lb1,lb2,lna1,lna2, lx1,lx2,ly1,ly2);
            wstep(y, ax1,ax2,ay1,ay2,aacc);
            wstep(y, bx1,bx2,by1,by2,bacc);

            y = bq32(v.z, hb0,hb1,hb2,hna1,hna2, hx1,hx2,hy1,hy2);
            y = bq32(y,   lb0,lb1,lb2,lna1,lna2, lx1,lx2,ly1,ly2);
            wstep(y, ax1,ax2,ay1,ay2,aacc);
            wstep(y, bx1,bx2,by1,by2,bacc);

            y = bq32(v.w, hb0,hb1,hb2,hna1,hna2, hx1,hx2,hy1,hy2);
            y = bq32(y,   lb0,lb1,lb2,lna1,lna2, lx1,lx2,ly1,ly2);
            wstep(y, ax1,ax2,ay1,ay2,aacc);
            wstep(y, bx1,bx2,by1,by2,bacc);
        }
        // Segment j=b-1 finished at the end of this block.
        if (b >= 1) {
            const int j = b - 1;
            float acc = ((j & 1) == 0) ? aacc : bacc;
            float e = __fmul_rn(acc, 0.00048828125f);          // /2048, exact pow2 scale
            float lv = __fmul_rn(10.0f, log10f(__fadd_rn(e, 1e-8f)));
            out[j] = lv;
        }
    }
}

__global__ __launch_bounds__(256)
void tf_reduce_kernel(const float* __restrict__ loud, float* __restrict__ out) {
    __shared__ double sh[256];
    const int per_band = ROWS * NSEG;       // 4960
    const int npairs   = NBANDS * per_band; // 39680
    double s = 0.0;
    for (int idx = threadIdx.x; idx < npairs; idx += 256) {
        int band = idx / per_band;
        int rs   = idx - band * per_band;
        float a = loud[(size_t)(band * 2 + 0) * per_band + rs]; // signal loudness
        float b = loud[(size_t)(band * 2 + 1) * per_band + rs]; // watermark loudness
        s += fabs((double)b - (double)a);
    }
    sh[threadIdx.x] = s;
    __syncthreads();
    for (int off = 128; off > 0; off >>= 1) {
        if (threadIdx.x < off) sh[threadIdx.x] += sh[threadIdx.x + off];
        __syncthreads();
    }
    // mean over bands of per-band means == global mean (equal counts)
    if (threadIdx.x == 0) out[0] = (float)(sh[0] / (double)npairs);
}

// Host-side coefficient computation: f64 with the reference's exact expression
// order, then cast each to f32 (mirrors tuple(np.float32(v / a0) ...)).
static void mk_hp(double cutoff, float* o) {
    const double w0    = 2.0 * M_PI * cutoff / 16000.0;
    const double alpha = sin(w0) / (2.0 * 0.707);
    const double cw    = cos(w0);
    const double b0 = (1.0 + cw) / 2.0;
    const double b1 = -(1.0 + cw);
    const double b2 = (1.0 + cw) / 2.0;
    const double a0 = 1.0 + alpha;
    const double a1 = -2.0 * cw;
    const double a2 = 1.0 - alpha;
    o[0] = (float)(b0 / a0); o[1] = (float)(b1 / a0); o[2] = (float)(b2 / a0);
    o[3] = (float)(a1 / a0); o[4] = (float)(a2 / a0);
}

static void mk_lp(double cutoff, float* o) {
    const double w0    = 2.0 * M_PI * cutoff / 16000.0;
    const double alpha = sin(w0) / (2.0 * 0.707);
    const double cw    = cos(w0);
    const double b0 = (1.0 - cw) / 2.0;
    const double b1 = 1.0 - cw;
    const double b2 = (1.0 - cw) / 2.0;
    const double a0 = 1.0 + alpha;
    const double a1 = -2.0 * cw;
    const double a2 = 1.0 - alpha;
    o[0] = (float)(b0 / a0); o[1] = (float)(b1 / a0); o[2] = (float)(b2 / a0);
    o[3] = (float)(a1 / a0); o[4] = (float)(a2 / a0);
}

extern "C" void kernel_launch(void* const* d_in, const int* in_sizes, int n_in,
                              void* d_out, int out_size, void* d_ws, size_t ws_size,
                              hipStream_t stream) {
    const float* sig = (const float*)d_in[0];
    const float* wm  = (const float*)d_in[1];
    float* loud = (float*)d_ws;   // 8*2*32*155 floats = 310 KiB

    AllCoefs C;
    for (int i = 0; i < NBANDS; ++i) {
        mk_hp(1000.0 * (double)i,       C.h[i]);   // low_cut  = i*SR/(2*NB) = 1000*i exactly
        mk_lp(1000.0 * (double)(i + 1), C.l[i]);   // high_cut = (i+1)*1000 exactly
    }

    tf_filter_kernel<<<NBANDS, 64, 0, stream>>>(sig, wm, loud, C);
    tf_reduce_kernel<<<1, 256, 0, stream>>>(loud, (float*)d_out);
}

// Round 4
// 4350.611 us; speedup vs baseline: 2.3503x; 2.3503x over previous
//
#include <hip/hip_runtime.h>
#include <cmath>

#ifndef M_PI
#define M_PI 3.14159265358979323846
#endif

#define T_LEN   160000
#define CHUNK   64
#define NCHUNK  2496          // 159744 / 64 ; covers all samples any segment uses
#define TOT_IT  (NCHUNK + 2)  // pipeline drain: w-waves lag hp by 2 chunks
#define NSEG    155
#define ROWS    32
#define NBANDS  8

struct AllCoefs {
    float h[NBANDS][5];   // b0 b1 b2 a1 a2 (a0-normalized, f32-cast like np.float32)
    float l[NBANDS][5];
};

// fp32 DF-I biquad, LLVM FMA-contraction pattern of the left-associated
// reference expression — verified BIT-EXACT vs the np reference (R3 absmax 0.0).
// Do not reassociate: bands 0/7 are marginally stable, rounding double-integrates.
__device__ __forceinline__ float bq32(float x,
                                      const float b0, const float b1, const float b2,
                                      const float na1, const float na2,
                                      float& x1, float& x2, float& y1, float& y2) {
    float s1 = __fmaf_rn(b0, x, __fmul_rn(b1, x1));
    float s2 = __fmaf_rn(b2, x2, s1);
    float s3 = __fmaf_rn(na1, y1, s2);
    float y  = __fmaf_rn(na2, y2, s3);
    x2 = x1; x1 = x;
    y2 = y1; y1 = y;
    return y;
}

// Weighting biquad b=(1,-2,1), a=(1,-1.8f,0.81f); b-products exact pow2.
__device__ __forceinline__ void wstep(float x, float& x1, float& x2,
                                      float& y1, float& y2, float& acc) {
    const float NA1 =  1.79999995231628417969f; // -np.float32(-1.8)
    const float NA2 = -0.810000002384185791f;   // -np.float32(0.81)
    float s1 = __fadd_rn(x, __fmul_rn(-2.0f, x1));
    float s2 = __fadd_rn(s1, x2);
    float s3 = __fmaf_rn(NA1, y1, s2);
    float y  = __fmaf_rn(NA2, y2, s3);
    x2 = x1; x1 = x;
    y2 = y1; y1 = y;
    acc = __fmaf_rn(y, y, acc);
}

// One block per band; 4 waves pipeline the cascade across the CU's 4 SIMDs:
//   wave0: highpass  (global prefetch 1 chunk ahead) -> ybA
//   wave1: lowpass   ybA(c) -> ybB, lags 1 chunk
//   wave2: weighting, even-parity segments, reads ybB, lags 2 chunks
//   wave3: weighting, odd-parity segments,  reads ybB, lags 2 chunks
// Every arithmetic op is identical (same order) to the R3 bit-exact kernel;
// only the schedule changes. LDS hand-off buffers are [t][lane] (conflict-free).
__global__ __launch_bounds__(256, 1)
void tf_pipe_kernel(const float* __restrict__ sig, const float* __restrict__ wm,
                    float* __restrict__ loud, AllCoefs C) {
    __shared__ float ybA[2][CHUNK * 64];   // hp -> lp, double-buffered (32 KiB)
    __shared__ float ybB[2][CHUNK * 64];   // lp -> w,  double-buffered (32 KiB)

    const int band = blockIdx.x;
    const int tid  = threadIdx.x;
    const int wid  = tid >> 6;
    const int lane = tid & 63;
    const int src  = lane >> 5;     // 0 = signal, 1 = watermark
    const int row  = lane & 31;

    const float hb0 = C.h[band][0], hb1 = C.h[band][1], hb2 = C.h[band][2];
    const float hna1 = -C.h[band][3], hna2 = -C.h[band][4];
    const float lb0 = C.l[band][0], lb1 = C.l[band][1], lb2 = C.l[band][2];
    const float lna1 = -C.l[band][3], lna2 = -C.l[band][4];

    const float* __restrict__ xrow = (src ? wm : sig) + (size_t)row * T_LEN;
    float* __restrict__ out = loud + ((size_t)(band * 2 + src) * ROWS + row) * NSEG;

    float x1 = 0.f, x2 = 0.f, y1 = 0.f, y2 = 0.f;   // filter state (per-wave role)
    float acc = 0.f;                                 // w-wave energy accumulator
    const int parity = (wid == 3) ? 1 : 0;           // wave2: even segs, wave3: odd

    float4 pf[16];                                   // hp prefetch buffer (chunk k+1)
    if (wid == 0) {
        const float4* p0 = (const float4*)xrow;      // preload chunk 0
        #pragma unroll
        for (int i = 0; i < 16; ++i) pf[i] = p0[i];
    }

    for (int iter = 0; iter < TOT_IT; ++iter) {
        if (wid == 0) {
            if (iter < NCHUNK) {
                const int k = iter;
                // prefetch chunk k+1 (k+1 <= 2496 -> max t = 159807 < 160000, in-bounds)
                const float4* np_ = (const float4*)(xrow + (size_t)(k + 1) * CHUNK);
                float* __restrict__ ob = ybA[k & 1];
                #pragma unroll
                for (int i = 0; i < 16; ++i) {
                    float4 v = pf[i];
                    pf[i] = np_[i];
                    float y;
                    y = bq32(v.x, hb0,hb1,hb2,hna1,hna2, x1,x2,y1,y2); ob[(4*i+0)*64 + lane] = y;
                    y = bq32(v.y, hb0,hb1,hb2,hna1,hna2, x1,x2,y1,y2); ob[(4*i+1)*64 + lane] = y;
                    y = bq32(v.z, hb0,hb1,hb2,hna1,hna2, x1,x2,y1,y2); ob[(4*i+2)*64 + lane] = y;
                    y = bq32(v.w, hb0,hb1,hb2,hna1,hna2, x1,x2,y1,y2); ob[(4*i+3)*64 + lane] = y;
                }
            }
        } else if (wid == 1) {
            if (iter >= 1 && iter <= NCHUNK) {
                const int c = iter - 1;
                const float* __restrict__ ib = ybA[c & 1];
                float* __restrict__ ob = ybB[c & 1];
                #pragma unroll 8
                for (int t = 0; t < CHUNK; ++t) {
                    float y = bq32(ib[t*64 + lane], lb0,lb1,lb2,lna1,lna2, x1,x2,y1,y2);
                    ob[t*64 + lane] = y;
                }
            }
        } else {
            if (iter >= 2) {
                const int c = iter - 2;
                const int b = c >> 4;                       // 1024-sample block index
                // segment j=b starts at chunk c=16b; reset this wave's parity state
                if ((c & 31) == (parity << 4) && b < NSEG) {
                    x1 = 0.f; x2 = 0.f; y1 = 0.f; y2 = 0.f; acc = 0.f;
                }
                const float* __restrict__ ib = ybB[c & 1];
                #pragma unroll 8
                for (int t = 0; t < CHUNK; ++t)
                    wstep(ib[t*64 + lane], x1, x2, y1, y2, acc);
                // segment j=b-1 ends after chunk c when c%16==15
                if ((c & 15) == 15) {
                    const int j = b - 1;
                    if (j >= 0 && (j & 1) == parity) {
                        float e  = __fmul_rn(acc, 0.00048828125f);  // /2048 exact
                        out[j] = __fmul_rn(10.0f, log10f(__fadd_rn(e, 1e-8f)));
                    }
                }
            }
        }
        __syncthreads();
    }
}

__global__ __launch_bounds__(256)
void tf_reduce_kernel(const float* __restrict__ loud, float* __restrict__ out) {
    __shared__ double sh[256];
    const int per_band = ROWS * NSEG;       // 4960
    const int npairs   = NBANDS * per_band; // 39680
    double s = 0.0;
    for (int idx = threadIdx.x; idx < npairs; idx += 256) {
        int band = idx / per_band;
        int rs   = idx - band * per_band;
        float a = loud[(size_t)(band * 2 + 0) * per_band + rs];
        float b = loud[(size_t)(band * 2 + 1) * per_band + rs];
        s += fabs((double)b - (double)a);
    }
    sh[threadIdx.x] = s;
    __syncthreads();
    for (int off = 128; off > 0; off >>= 1) {
        if (threadIdx.x < off) sh[threadIdx.x] += sh[threadIdx.x + off];
        __syncthreads();
    }
    if (threadIdx.x == 0) out[0] = (float)(sh[0] / (double)npairs);
}

// Host-side coefficients: f64 with the reference's exact expression order,
// then cast each to f32 (mirrors tuple(np.float32(v / a0) ...)).
static void mk_hp(double cutoff, float* o) {
    const double w0    = 2.0 * M_PI * cutoff / 16000.0;
    const double alpha = sin(w0) / (2.0 * 0.707);
    const double cw    = cos(w0);
    const double b0 = (1.0 + cw) / 2.0;
    const double b1 = -(1.0 + cw);
    const double b2 = (1.0 + cw) / 2.0;
    const double a0 = 1.0 + alpha;
    const double a1 = -2.0 * cw;
    const double a2 = 1.0 - alpha;
    o[0] = (float)(b0 / a0); o[1] = (float)(b1 / a0); o[2] = (float)(b2 / a0);
    o[3] = (float)(a1 / a0); o[4] = (float)(a2 / a0);
}

static void mk_lp(double cutoff, float* o) {
    const double w0    = 2.0 * M_PI * cutoff / 16000.0;
    const double alpha = sin(w0) / (2.0 * 0.707);
    const double cw    = cos(w0);
    const double b0 = (1.0 - cw) / 2.0;
    const double b1 = 1.0 - cw;
    const double b2 = (1.0 - cw) / 2.0;
    const double a0 = 1.0 + alpha;
    const double a1 = -2.0 * cw;
    const double a2 = 1.0 - alpha;
    o[0] = (float)(b0 / a0); o[1] = (float)(b1 / a0); o[2] = (float)(b2 / a0);
    o[3] = (float)(a1 / a0); o[4] = (float)(a2 / a0);
}

extern "C" void kernel_launch(void* const* d_in, const int* in_sizes, int n_in,
                              void* d_out, int out_size, void* d_ws, size_t ws_size,
                              hipStream_t stream) {
    const float* sig = (const float*)d_in[0];
    const float* wm  = (const float*)d_in[1];
    float* loud = (float*)d_ws;   // 8*2*32*155 floats = 310 KiB

    AllCoefs C;
    for (int i = 0; i < NBANDS; ++i) {
        mk_hp(1000.0 * (double)i,       C.h[i]);
        mk_lp(1000.0 * (double)(i + 1), C.l[i]);
    }

    tf_pipe_kernel<<<NBANDS, 256, 0, stream>>>(sig, wm, loud, C);
    tf_reduce_kernel<<<1, 256, 0, stream>>>(loud, (float*)d_out);
}